// Round 2
// 667.872 us; speedup vs baseline: 1.0140x; 1.0140x over previous
//
#include <hip/hip_runtime.h>
#include <math.h>

#define N_NODES 1024
#define HDIM    128
#define NT      512            // threads per block (8 waves)
#define NG      (NT / 32)      // 16 groups of 32 lanes
#define NW      (NT / 64)      // 8 waves

typedef float floatx4 __attribute__((ext_vector_type(4)));

// One block per node i.
//  Phase 1: ballot-compacted, fully SORTED active-j list (no shared atomics).
//  Phase 2: each 32-lane group streams one 512 B T-row + nf-row per stage,
//           2-stage register pipeline with the list index prefetched one
//           stage further ahead -> loads stay in flight across iterations.
//  Phase 3: 768 GRU matvec rows (gi: w_ih x agg, gh: w_hh x nf_i) over all
//           512 threads, weights are L2-resident.
//  Phase 4: gates + output.
__global__ __launch_bounds__(NT, 8) void motif_gru_kernel(
    const float* __restrict__ nf,     // [N, H]
    const int*   __restrict__ adj,    // [N, N]
    const float* __restrict__ T,      // [N*N, H]
    const float* __restrict__ w_ih,   // [3H, H]
    const float* __restrict__ w_hh,   // [3H, H]
    const float* __restrict__ b_ih,   // [3H]
    const float* __restrict__ b_hh,   // [3H]
    float*       __restrict__ out)    // [N, H]
{
    const int i   = blockIdx.x;
    const int tid = threadIdx.x;

    __shared__ int   s_list[N_NODES];     // sorted active-j list
    __shared__ int   s_wcnt[NW];
    __shared__ int   s_woff[NW];
    __shared__ int   s_cnt;
    __shared__ float s_red[NG][HDIM];     // per-group partial sums
    __shared__ float s_agg[HDIM];
    __shared__ float s_nfi[HDIM];
    __shared__ float s_gi[3 * HDIM];
    __shared__ float s_gh[3 * HDIM];

    const int w      = tid >> 6;          // wave 0..7
    const int lane64 = tid & 63;

    // ---- Phase 1: sorted compaction. Wave w owns j in [w*128, w*128+128).
    const int* adj_row = adj + (size_t)i * N_NODES;
    const int  jbase   = w * (N_NODES / NW);
    const int  a0 = adj_row[jbase + lane64];
    const int  a1 = adj_row[jbase + 64 + lane64];
    const unsigned long long m0 = __ballot(a0 != 0);
    const unsigned long long m1 = __ballot(a1 != 0);
    const int c0 = __popcll(m0);
    if (lane64 == 0) s_wcnt[w] = c0 + __popcll(m1);
    if (tid < HDIM) s_nfi[tid] = nf[(size_t)i * HDIM + tid];
    __syncthreads();
    if (tid == 0) {
        int s = 0;
        #pragma unroll
        for (int ww = 0; ww < NW; ++ww) { s_woff[ww] = s; s += s_wcnt[ww]; }
        s_cnt = s;
    }
    __syncthreads();
    {
        const unsigned long long below = (1ull << lane64) - 1ull;
        const int off = s_woff[w];
        if (a0) s_list[off + __popcll(m0 & below)]      = jbase + lane64;
        if (a1) s_list[off + c0 + __popcll(m1 & below)] = jbase + 64 + lane64;
    }
    __syncthreads();
    const int cnt = s_cnt;

    // ---- Phase 2: agg[i,h] = sum_{active j, ascending} nf[j,h] * T[i,j,h]
    const int g    = tid >> 5;            // group 0..15
    const int lane = tid & 31;            // 4 floats each -> 128

    const floatx4* Tv  = reinterpret_cast<const floatx4*>(T) + (size_t)i * N_NODES * 32;
    const floatx4* nfv = reinterpret_cast<const floatx4*>(nf);

    floatx4 acc = (floatx4)(0.f);

    // pipeline state: (tB,nB) in flight for current stage; jNext prefetched
    int  rNext = g;
    bool vB    = (rNext < cnt);
    floatx4 tB = (floatx4)(0.f);
    floatx4 nB = (floatx4)(0.f);
    if (vB) {
        const int j = s_list[rNext];
        tB = __builtin_nontemporal_load(&Tv[(size_t)j * 32 + lane]);
        nB = nfv[(size_t)j * 32 + lane];
    }
    rNext += NG;
    bool vNext = (rNext < cnt);
    int  jNext = vNext ? s_list[rNext] : 0;

    while (vB) {
        // issue loads for stage k+1 (index already in a register)
        floatx4 tC = (floatx4)(0.f);
        floatx4 nC = (floatx4)(0.f);
        const bool vC = vNext;
        if (vC) {
            tC = __builtin_nontemporal_load(&Tv[(size_t)jNext * 32 + lane]);
            nC = nfv[(size_t)jNext * 32 + lane];
        }
        // prefetch index for stage k+2 (hides ds_read latency)
        rNext += NG;
        vNext = (rNext < cnt);
        jNext = vNext ? s_list[rNext] : 0;

        // consume stage k
        acc += tB * nB;

        tB = tC; nB = nC; vB = vC;
    }

    *reinterpret_cast<floatx4*>(&s_red[g][lane * 4]) = acc;
    __syncthreads();

    if (tid < HDIM) {
        float s = 0.f;
        #pragma unroll
        for (int gg = 0; gg < NG; ++gg) s += s_red[gg][tid];
        s_agg[tid] = s;
    }
    __syncthreads();

    // ---- Phase 3: 768 dot-product rows over 512 threads.
    // rows 0..383   -> gi[c] = w_ih[c,:] . agg  + b_ih[c]
    // rows 384..767 -> gh[c] = w_hh[c,:] . nf_i + b_hh[c]
    const floatx4* aggv = reinterpret_cast<const floatx4*>(s_agg);
    const floatx4* nfiv = reinterpret_cast<const floatx4*>(s_nfi);
    for (int cc = tid; cc < 6 * HDIM; cc += NT) {
        const bool isin = cc < 3 * HDIM;
        const int  c    = isin ? cc : cc - 3 * HDIM;
        const floatx4* wp = reinterpret_cast<const floatx4*>(
            (isin ? w_ih : w_hh) + (size_t)c * HDIM);
        const floatx4* xv = isin ? aggv : nfiv;
        float s = 0.f;
        #pragma unroll 4
        for (int k = 0; k < HDIM / 4; ++k) {
            floatx4 w4 = wp[k];
            floatx4 x4 = xv[k];
            floatx4 p  = w4 * x4;
            s += p.x + p.y + p.z + p.w;
        }
        if (isin) s_gi[c] = s + b_ih[c];
        else      s_gh[c] = s + b_hh[c];
    }
    __syncthreads();

    // ---- Phase 4: gates + output
    if (tid < HDIM) {
        const float r  = 1.f / (1.f + expf(-(s_gi[tid] + s_gh[tid])));
        const float z  = 1.f / (1.f + expf(-(s_gi[HDIM + tid] + s_gh[HDIM + tid])));
        const float nn = tanhf(s_gi[2 * HDIM + tid] + r * s_gh[2 * HDIM + tid]);
        out[(size_t)i * HDIM + tid] = (1.f - z) * nn + z * s_nfi[tid];
    }
}

extern "C" void kernel_launch(void* const* d_in, const int* in_sizes, int n_in,
                              void* d_out, int out_size, void* d_ws, size_t ws_size,
                              hipStream_t stream) {
    const float* nf   = (const float*)d_in[0];
    const int*   adj  = (const int*)d_in[1];
    const float* T    = (const float*)d_in[2];
    const float* w_ih = (const float*)d_in[3];
    const float* w_hh = (const float*)d_in[4];
    const float* b_ih = (const float*)d_in[5];
    const float* b_hh = (const float*)d_in[6];
    float* out = (float*)d_out;

    motif_gru_kernel<<<dim3(N_NODES), dim3(NT), 0, stream>>>(
        nf, adj, T, w_ih, w_hh, b_ih, b_hh, out);
}